// Round 3
// baseline (424.111 us; speedup 1.0000x reference)
//
#include <hip/hip_runtime.h>

#define EMBED 64
#define BATCH 4096
#define CHUNK 64    // nnz per wave
#define G     8     // row-gathers in flight per inner batch (4 nnz each... 8 iters x 4 nnz = 32 nnz)

// Wave handles 64 consecutive nnz. Meta (bid,fid,val) loaded once, coalesced,
// one element per lane; broadcast to 16-lane groups via __shfl. Each 16-lane
// group gathers one 256 B embedding row per iteration as float4/lane
// (1 KB per wave-instruction, 8 independent gathers in flight).
// Partial s/sq flushed by atomicAdd on sorted row boundaries.
__global__ __launch_bounds__(256) void fm_accum(
    const float4* __restrict__ emb4,   // [VOCAB * 16] float4
    const float*  __restrict__ vals,
    const int*    __restrict__ bids,
    const int*    __restrict__ fids,
    float* __restrict__ s_buf,         // [BATCH * EMBED]
    float* __restrict__ q_buf,         // [BATCH * EMBED]
    int nnz)
{
    const int gid  = blockIdx.x * blockDim.x + threadIdx.x;
    const int wave = gid >> 6;
    const int lane = threadIdx.x & 63;
    const int grp  = lane >> 4;        // group's nnz slot within a 4-nnz iter
    const int sub  = lane & 15;        // which float4 of the 64-dim row

    const int base = wave * CHUNK;
    if (base >= nnz) return;

    // own meta: one coalesced load per array, one nnz per lane
    const int  myi  = min(base + lane, nnz - 1);
    const int  my_b = bids[myi];
    const int  my_f = fids[myi];
    const float my_v = (base + lane < nnz) ? vals[myi] : 0.f;

    float4 s = make_float4(0.f, 0.f, 0.f, 0.f);
    float4 q = make_float4(0.f, 0.f, 0.f, 0.f);
    int cur = -1;

    #pragma unroll
    for (int half = 0; half < 2; ++half) {
        const int j0 = half * 4 * G;
        int r[G]; float v[G]; float4 e[G];

        #pragma unroll
        for (int g = 0; g < G; ++g) {
            const int j = j0 + 4 * g + grp;       // nnz slot 0..63 in chunk
            r[g] = __shfl(my_b, j);
            v[g] = __shfl(my_v, j);
            const int f = __shfl(my_f, j);
            e[g] = emb4[(size_t)f * 16 + sub];    // independent, in flight
        }

        #pragma unroll
        for (int g = 0; g < G; ++g) {
            if (r[g] != cur) {
                if (cur >= 0) {
                    float* sp = s_buf + (size_t)cur * EMBED + (sub << 2);
                    float* qp = q_buf + (size_t)cur * EMBED + (sub << 2);
                    atomicAdd(sp + 0, s.x); atomicAdd(sp + 1, s.y);
                    atomicAdd(sp + 2, s.z); atomicAdd(sp + 3, s.w);
                    atomicAdd(qp + 0, q.x); atomicAdd(qp + 1, q.y);
                    atomicAdd(qp + 2, q.z); atomicAdd(qp + 3, q.w);
                }
                cur = r[g];
                s = make_float4(0.f, 0.f, 0.f, 0.f);
                q = make_float4(0.f, 0.f, 0.f, 0.f);
            }
            const float ax = v[g] * e[g].x, ay = v[g] * e[g].y;
            const float az = v[g] * e[g].z, aw = v[g] * e[g].w;
            s.x += ax;      s.y += ay;      s.z += az;      s.w += aw;
            q.x += ax * ax; q.y += ay * ay; q.z += az * az; q.w += aw * aw;
        }
    }

    if (cur >= 0) {
        float* sp = s_buf + (size_t)cur * EMBED + (sub << 2);
        float* qp = q_buf + (size_t)cur * EMBED + (sub << 2);
        atomicAdd(sp + 0, s.x); atomicAdd(sp + 1, s.y);
        atomicAdd(sp + 2, s.z); atomicAdd(sp + 3, s.w);
        atomicAdd(qp + 0, q.x); atomicAdd(qp + 1, q.y);
        atomicAdd(qp + 2, q.z); atomicAdd(qp + 3, q.w);
    }
}

__global__ __launch_bounds__(256) void fm_final(
    const float4* __restrict__ sb, const float4* __restrict__ qb,
    float4* __restrict__ out, int n4)
{
    int i = blockIdx.x * blockDim.x + threadIdx.x;
    if (i < n4) {
        float4 s = sb[i], q = qb[i], o;
        o.x = 0.5f * (s.x * s.x - q.x);
        o.y = 0.5f * (s.y * s.y - q.y);
        o.z = 0.5f * (s.z * s.z - q.z);
        o.w = 0.5f * (s.w * s.w - q.w);
        out[i] = o;
    }
}

extern "C" void kernel_launch(void* const* d_in, const int* in_sizes, int n_in,
                              void* d_out, int out_size, void* d_ws, size_t ws_size,
                              hipStream_t stream) {
    const float4* emb4 = (const float4*)d_in[0];
    const float*  vals = (const float*)d_in[1];
    const int*    bids = (const int*)d_in[2];
    const int*    fids = (const int*)d_in[3];
    float*        out  = (float*)d_out;
    const int nnz = in_sizes[1];

    float* s_buf = (float*)d_ws;
    float* q_buf = s_buf + (size_t)BATCH * EMBED;

    // zero the 2 MB partial-sum workspace (ws is re-poisoned 0xAA each launch)
    hipMemsetAsync(d_ws, 0, (size_t)BATCH * EMBED * 2 * sizeof(float), stream);

    const int waves   = (nnz + CHUNK - 1) / CHUNK;   // 12800
    const int blocks  = (waves * 64 + 255) / 256;    // 3200
    fm_accum<<<dim3(blocks), dim3(256), 0, stream>>>(emb4, vals, bids, fids,
                                                     s_buf, q_buf, nnz);

    const int n4 = BATCH * EMBED / 4;
    fm_final<<<dim3((n4 + 255) / 256), dim3(256), 0, stream>>>(
        (const float4*)s_buf, (const float4*)q_buf, (float4*)out, n4);
}

// Round 4
// 336.299 us; speedup vs baseline: 1.2611x; 1.2611x over previous
//
#include <hip/hip_runtime.h>

#define EMBED 64
#define BATCH 4096
#define G     8     // row-gathers in flight per batch

// Phase 1: find each batch row's [start,end) in the sorted batch_ids.
// start[] is pre-set to -1 (empty rows); end[] only read when start>=0.
__global__ __launch_bounds__(256) void seg_bounds(
    const int* __restrict__ bids, int* __restrict__ start,
    int* __restrict__ end_, int nnz)
{
    int i = blockIdx.x * blockDim.x + threadIdx.x;
    if (i >= nnz) return;
    int b = bids[i];
    if (i == 0 || bids[i - 1] != b) start[b] = i;
    if (i == nnz - 1 || bids[i + 1] != b) end_[b] = i + 1;
}

// Phase 2: one wave per output row. 16-lane groups each gather one 256 B
// embedding row per step as float4/lane; meta (fid,val) loaded coalesced
// once per 64-nnz window (next window prefetched) and broadcast via __shfl.
// No atomics: partials live in registers, combined by 2 shfl_xor stages,
// stored directly to out.
__global__ __launch_bounds__(256) void fm_row(
    const float4* __restrict__ emb4,   // [VOCAB*16] float4
    const float*  __restrict__ vals,
    const int*    __restrict__ fids,
    const int*    __restrict__ start,
    const int*    __restrict__ end_,
    float4*       __restrict__ out4)   // [BATCH*16] float4
{
    const int wave = (blockIdx.x * blockDim.x + threadIdx.x) >> 6;
    const int lane = threadIdx.x & 63;
    const int grp  = lane >> 4;   // which nnz slot within a 4-nnz step
    const int sub  = lane & 15;   // which float4 of the 64-dim row
    const int r    = wave;
    if (r >= BATCH) return;

    const int s0 = start[r];
    if (s0 < 0) {                 // empty row
        if (grp == 0) out4[r * 16 + sub] = make_float4(0.f, 0.f, 0.f, 0.f);
        return;
    }
    const int s1 = end_[r];

    // prime first meta window (coalesced, one nnz per lane)
    int   idx   = s0 + lane;
    int   f_cur = fids[min(idx, s1 - 1)];
    float v_cur = (idx < s1) ? vals[idx] : 0.f;

    float4 s = make_float4(0.f, 0.f, 0.f, 0.f);
    float4 q = make_float4(0.f, 0.f, 0.f, 0.f);

    for (int w0 = s0; w0 < s1; w0 += 64) {
        // prefetch next meta window while gathering this one
        int nbase = w0 + 64;
        int f_nxt = 0; float v_nxt = 0.f;
        if (nbase < s1) {
            int nidx = nbase + lane;
            int c    = min(nidx, s1 - 1);
            f_nxt = fids[c];
            v_nxt = (nidx < s1) ? vals[nidx] : 0.f;
        }
        const int lim = min(64, s1 - w0);
        #pragma unroll
        for (int b = 0; b < 2; ++b) {
            if (b * 32 >= lim) break;
            float4 e[G]; float vv[G];
            #pragma unroll
            for (int g = 0; g < G; ++g) {
                int j  = b * 32 + 4 * g + grp;       // nnz slot in window
                int f  = __shfl(f_cur, j);
                vv[g]  = __shfl(v_cur, j);
                e[g]   = emb4[(size_t)f * 16 + sub]; // 8 gathers in flight
            }
            #pragma unroll
            for (int g = 0; g < G; ++g) {
                float ax = vv[g] * e[g].x, ay = vv[g] * e[g].y;
                float az = vv[g] * e[g].z, aw = vv[g] * e[g].w;
                s.x += ax;      s.y += ay;      s.z += az;      s.w += aw;
                q.x += ax * ax; q.y += ay * ay; q.z += az * az; q.w += aw * aw;
            }
        }
        f_cur = f_nxt; v_cur = v_nxt;
    }

    // combine the 4 group partials (lane bits 4,5)
    #pragma unroll
    for (int m = 16; m <= 32; m <<= 1) {
        s.x += __shfl_xor(s.x, m); s.y += __shfl_xor(s.y, m);
        s.z += __shfl_xor(s.z, m); s.w += __shfl_xor(s.w, m);
        q.x += __shfl_xor(q.x, m); q.y += __shfl_xor(q.y, m);
        q.z += __shfl_xor(q.z, m); q.w += __shfl_xor(q.w, m);
    }
    if (grp == 0) {
        float4 o;
        o.x = 0.5f * (s.x * s.x - q.x);
        o.y = 0.5f * (s.y * s.y - q.y);
        o.z = 0.5f * (s.z * s.z - q.z);
        o.w = 0.5f * (s.w * s.w - q.w);
        out4[r * 16 + sub] = o;
    }
}

extern "C" void kernel_launch(void* const* d_in, const int* in_sizes, int n_in,
                              void* d_out, int out_size, void* d_ws, size_t ws_size,
                              hipStream_t stream) {
    const float4* emb4 = (const float4*)d_in[0];
    const float*  vals = (const float*)d_in[1];
    const int*    bids = (const int*)d_in[2];
    const int*    fids = (const int*)d_in[3];
    float4*       out4 = (float4*)d_out;
    const int nnz = in_sizes[1];

    int* start = (int*)d_ws;
    int* end_  = start + BATCH;

    // start[] = -1 (ws is re-poisoned 0xAA each launch; must init ourselves)
    hipMemsetAsync(start, 0xFF, BATCH * sizeof(int), stream);

    seg_bounds<<<dim3((nnz + 255) / 256), dim3(256), 0, stream>>>(
        bids, start, end_, nnz);

    const int blocks = BATCH / 4;   // 4 waves (rows) per 256-thread block
    fm_row<<<dim3(blocks), dim3(256), 0, stream>>>(
        emb4, vals, fids, start, end_, out4);
}